// Round 6
// baseline (592.657 us; speedup 1.0000x reference)
//
#include <hip/hip_runtime.h>

// Problem dims
#define BB 64
#define SS 2048
#define INDIM 256
#define HH 512
#define EE 256
#define OUTD 32000

typedef __attribute__((ext_vector_type(8))) short short8;
typedef __attribute__((ext_vector_type(4))) float floatx4;

#define LOG2E 1.4426950408889634f

// ---- helpers ----
__device__ __forceinline__ unsigned short f2bf(float f) {
  unsigned u = __float_as_uint(f);
  return (unsigned short)((u + 0x7FFFu + ((u >> 16) & 1u)) >> 16);  // RNE
}
__device__ __forceinline__ unsigned pk2(float a, float b) {
  return (unsigned)f2bf(a) | ((unsigned)f2bf(b) << 16);
}
__device__ __forceinline__ float bf2f(unsigned short u) {
  return __uint_as_float((unsigned)u << 16);
}
__device__ __forceinline__ float fast_tanh(float x) {
  float e = __builtin_amdgcn_exp2f(x * 2.8853900817779268f);
  return 1.0f - 2.0f * __builtin_amdgcn_rcpf(e + 1.0f);
}
__device__ __forceinline__ float fast_sigmoid(float x) {
  float e = __builtin_amdgcn_exp2f(-x * LOG2E);
  return __builtin_amdgcn_rcpf(1.0f + e);
}

// global -> LDS 16B DMA (zero VGPR data path; vmcnt-tracked)
typedef __attribute__((address_space(1))) const void g1void;
typedef __attribute__((address_space(3))) void l3void;
__device__ __forceinline__ void dma16(const void* g, void* l) {
  __builtin_amdgcn_global_load_lds((g1void*)g, (l3void*)l, 16, 0, 0);
}

// ws layout (bytes)
#define WS_W1T   0          // 256x512 bf16 W1^T              : 262144
#define WS_HBP   262144     // 8 x 64x256 f32 hb partials     : 524288
#define WS_CTX   786432     // 64x512 f32 normalized ctx      : 131072
#define WS_NHBF  917504     // 64x512 bf16 new hidden         : 65536
#define WS_Z     983040     // 64x512 f32 update gate         : 131072
#define WS_RH    1114112    // 64x512 f32 r*hidden            : 131072
#define WS_GP    1245184    // 40 x 64x512 f32 gate partials  : 5242880
#define WS_NP    6488064    // 20 x 64x512 f32 newh partials  : 2621440
#define WS_CTXP  9109504    // 8192x512 f32 ctx partials      : 16777216
#define WS_SUMP  25886720   // 2048 f32 exp-sum partials      : 8192
#define WS_ENCB  25894912   // 131072x512 bf16 swizzled enc   : 134217728

// ---- prep: transpose+convert W1 -> bf16 [e][k] ----
__global__ void k_prep(const float* __restrict__ W1, unsigned short* __restrict__ W1t) {
  int idx = blockIdx.x * 256 + threadIdx.x;   // idx = k*256 + e (coalesced read)
  int k = idx >> 8, e = idx & 255;
  W1t[e * HH + k] = f2bf(W1[idx]);
}

// ---- conv: enc f32 -> bf16, bank-swizzled row layout ----
// Pure streaming (reads linear, writes full permuted 128B lines). 16B chunk c
// (8 bf16) of row r lands at chunk c^(r&7): consumers get conflict-free LDS
// reads from a LINEAR DMA copy of the row.
__global__ __launch_bounds__(256) void k_conv(const float* __restrict__ enc,
                                              unsigned short* __restrict__ encb) {
  int tid = threadIdx.x;
  int r_loc = tid >> 3, c0 = tid & 7;
  int row = blockIdx.x * 32 + r_loc;
  int rs = row & 7;
  const float* src = enc + (size_t)row * HH;
  unsigned short* dst = encb + (size_t)row * HH;
#pragma unroll
  for (int k = 0; k < 8; ++k) {
    int c = c0 + k * 8;
    float4 f0 = *(const float4*)(src + c * 8);
    float4 f1 = *(const float4*)(src + c * 8 + 4);
    uint4 w;
    w.x = pk2(f0.x, f0.y); w.y = pk2(f0.z, f0.w);
    w.z = pk2(f1.x, f1.y); w.w = pk2(f1.z, f1.w);
    *(uint4*)(dst + (c ^ rs) * 8) = w;
  }
}

// ---- hb partials: hbp[seg][b][e] = (seg==0? W1b[e]:0) + hidden[b][seg*64..]@W2 ----
// K-split 8 -> 128 blocks (was 32): 4x the parallelism, 64 serial iters.
__global__ __launch_bounds__(256) void k_hb(const float* __restrict__ hidden,
                                            const float* __restrict__ W2,
                                            const float* __restrict__ W1b,
                                            float* __restrict__ hbp) {
  int b0 = blockIdx.x * 4, seg = blockIdx.y, e = threadIdx.x;
  int h0 = seg * 64;
  float a0 = 0, a1 = 0, a2 = 0, a3 = 0;
  if (seg == 0) { a0 = a1 = a2 = a3 = W1b[e]; }
  for (int h = 0; h < 64; ++h) {
    float w = W2[(h0 + h) * EE + e];
    a0 += hidden[(b0 + 0) * HH + h0 + h] * w;
    a1 += hidden[(b0 + 1) * HH + h0 + h] * w;
    a2 += hidden[(b0 + 2) * HH + h0 + h] * w;
    a3 += hidden[(b0 + 3) * HH + h0 + h] * w;
  }
  float* o = hbp + (size_t)seg * BB * EE;
  o[(b0 + 0) * EE + e] = a0; o[(b0 + 1) * EE + e] = a1;
  o[(b0 + 2) * EE + e] = a2; o[(b0 + 3) * EE + e] = a3;
}

// ---- fused scores + exp + unnormalized context partials (bf16 input) ----
// grid 2048 (BS/64), block 256 (4 waves = 4 N-tiles), 64x512 bf16 tile.
// DMA is LINEAR src+dst (swizzle pre-applied by k_conv); one barrier; then a
// barrier-free unrolled MFMA phase: ds_read_b128 A-frags at phys chunk
// (kb*4+quad)^(l15&7) -> 8 lanes/bank-group (minimum rounds), B-frags stream
// from L2, no conversion anywhere in the loop.
__global__ __launch_bounds__(256, 2) void k_scores(
    const unsigned short* __restrict__ encb, const unsigned short* __restrict__ W1t,
    const float* __restrict__ hbp, const float* __restrict__ vw,
    float* __restrict__ attn, float* __restrict__ ctxp, float* __restrict__ sump) {
  __shared__ unsigned short Afull[64 * 512];   // 65536 B, swizzled chunks
  __shared__ float hb_s[EE], v_s[EE];
  __shared__ float red[4 * 64];
  __shared__ float wbuf[64];

  int tid = threadIdx.x;
  int m0 = blockIdx.x * 64;
  int b = blockIdx.x >> 5;                 // 32 tiles per batch
  int sloc = (blockIdx.x & 31) * 64;
  int lane = tid & 63, wn = tid >> 6;      // wave = one 64-wide N tile
  int l15 = lane & 15, quad = lane >> 4;

  // ---- DMA staging: wave wn -> rows wn*16..+16, 1KB (one instr) per row ----
#pragma unroll
  for (int rr = 0; rr < 16; ++rr) {
    int r = wn * 16 + rr;
    dma16(encb + (size_t)(m0 + r) * HH + lane * 8, Afull + r * HH);
  }
  {
    float hbv = 0.0f;
#pragma unroll
    for (int s = 0; s < 8; ++s) hbv += hbp[s * BB * EE + b * EE + tid];
    hb_s[tid] = hbv;
    v_s[tid] = vw[tid];
  }
  __syncthreads();   // drains DMA + LDS writes; tile valid

  // ---- barrier-free MFMA phase: M=64 (4 frags), N=64 (4 frags), K=512 ----
  floatx4 acc[4][4];
#pragma unroll
  for (int i = 0; i < 4; ++i)
#pragma unroll
    for (int j = 0; j < 4; ++j) acc[i][j] = (floatx4)0.0f;

  const unsigned short* bbase = W1t + (size_t)(wn * 64) * HH;
#pragma unroll
  for (int kb = 0; kb < 16; ++kb) {
    short8 a[4];
#pragma unroll
    for (int i = 0; i < 4; ++i) {
      int r = i * 16 + l15;
      int pc = (kb * 4 + quad) ^ (l15 & 7);      // phys 16B chunk
      a[i] = *(const short8*)(Afull + r * HH + pc * 8);
    }
#pragma unroll
    for (int j = 0; j < 4; ++j) {
      short8 bfr = *(const short8*)(bbase + (size_t)(j * 16 + l15) * HH + kb * 32 + quad * 8);
#pragma unroll
      for (int i = 0; i < 4; ++i)
        acc[i][j] = __builtin_amdgcn_mfma_f32_16x16x32_bf16(a[i], bfr, acc[i][j], 0, 0, 0);
    }
  }
  __syncthreads();

  // score epilogue: score[m] = sum_e tanh(C+hb[e])*v[e]; C/D: col(e)=l15, row=quad*4+r
#pragma unroll
  for (int i = 0; i < 4; ++i)
#pragma unroll
    for (int r = 0; r < 4; ++r) {
      float s = 0.0f;
#pragma unroll
      for (int j = 0; j < 4; ++j) {
        int e = wn * 64 + j * 16 + l15;
        s += fast_tanh(acc[i][j][r] + hb_s[e]) * v_s[e];
      }
#pragma unroll
      for (int off = 1; off < 16; off <<= 1) s += __shfl_xor(s, off, 64);
      if (l15 == 0) red[wn * 64 + i * 16 + quad * 4 + r] = s;
    }
  __syncthreads();
  if (tid < 64) {
    float sc = red[tid] + red[64 + tid] + red[128 + tid] + red[192 + tid];
    float e = __builtin_amdgcn_exp2f(sc * LOG2E);   // |sc| <= sum|v| ~ 13: safe
    wbuf[tid] = e;
    attn[b * SS + sloc + tid] = e;                  // unnormalized; k_norm divides
    float s = e;
#pragma unroll
    for (int off = 1; off < 64; off <<= 1) s += __shfl_xor(s, off, 64);
    if (tid == 0) sump[blockIdx.x] = s;
  }
  __syncthreads();

  // pass 2: ctx partials. Wave wn covers rows [wn*16,+16); lane reads logical
  // chunk `lane` at phys lane^(r&7): permutation, conflict-free.
  float cacc[8];
#pragma unroll
  for (int j = 0; j < 8; ++j) cacc[j] = 0.0f;
#pragma unroll
  for (int rr = 0; rr < 16; ++rr) {
    int r = wn * 16 + rr;
    float w = wbuf[r];
    int pc = lane ^ (r & 7);
    short8 av = *(const short8*)(Afull + r * HH + pc * 8);
#pragma unroll
    for (int j = 0; j < 8; ++j) cacc[j] += w * bf2f((unsigned short)av[j]);
  }
  float4 c0, c1;
  c0.x = cacc[0]; c0.y = cacc[1]; c0.z = cacc[2]; c0.w = cacc[3];
  c1.x = cacc[4]; c1.y = cacc[5]; c1.z = cacc[6]; c1.w = cacc[7];
  float* cp = ctxp + ((size_t)blockIdx.x * 4 + wn) * HH + lane * 8;
  *(float4*)cp = c0;
  *(float4*)(cp + 4) = c1;
}

// ---- reduce partials, normalize attn + ctx ----
__global__ __launch_bounds__(512) void k_norm(float* __restrict__ attn,
                                              const float* __restrict__ ctxp,
                                              const float* __restrict__ sump,
                                              float* __restrict__ ctx) {
  int b = blockIdx.x, tid = threadIdx.x;
  float s = 0.0f;
#pragma unroll
  for (int t = 0; t < 32; ++t) s += sump[b * 32 + t];
  float inv = 1.0f / s;
#pragma unroll
  for (int i = 0; i < 4; ++i) attn[b * SS + tid + i * 512] *= inv;
  float c = 0.0f;
#pragma unroll 8
  for (int t = 0; t < 128; ++t) c += ctxp[(size_t)(b * 128 + t) * HH + tid];
  ctx[b * HH + tid] = c * inv;
}

// ---- K-split partial GEMM core: 64 virtual-K rows, 4 batches, 20 segs ----
// virtual K layout [ x(256) | ctx(512) | hv(512) ]
__device__ __forceinline__ void part_seg(
    const float* __restrict__ Wx, const float* __restrict__ Wh,
    const float* __restrict__ x, const float* __restrict__ ctx,
    const float* __restrict__ hv, int seg, int b0, int h,
    float* __restrict__ outp) {
  const float* wseg;
  const float* a0; const float* a1; const float* a2; const float* a3;
  int vk0 = seg * 64;
  if (seg < 4) {
    wseg = Wx + (size_t)vk0 * HH;
    a0 = x + (b0 + 0) * INDIM + vk0;       a1 = x + (b0 + 1) * INDIM + vk0;
    a2 = x + (b0 + 2) * INDIM + vk0;       a3 = x + (b0 + 3) * INDIM + vk0;
  } else if (seg < 12) {
    wseg = Wx + (size_t)vk0 * HH;
    int off = vk0 - 256;
    a0 = ctx + (b0 + 0) * HH + off;        a1 = ctx + (b0 + 1) * HH + off;
    a2 = ctx + (b0 + 2) * HH + off;        a3 = ctx + (b0 + 3) * HH + off;
  } else {
    int off = vk0 - 768;
    wseg = Wh + (size_t)off * HH;
    a0 = hv + (b0 + 0) * HH + off;         a1 = hv + (b0 + 1) * HH + off;
    a2 = hv + (b0 + 2) * HH + off;         a3 = hv + (b0 + 3) * HH + off;
  }
  float s0 = 0, s1 = 0, s2 = 0, s3 = 0;
  for (int i = 0; i < 64; ++i) {
    float w = wseg[i * HH + h];
    s0 += a0[i] * w; s1 += a1[i] * w;
    s2 += a2[i] * w; s3 += a3[i] * w;
  }
  outp[(b0 + 0) * HH + h] = s0; outp[(b0 + 1) * HH + h] = s1;
  outp[(b0 + 2) * HH + h] = s2; outp[(b0 + 3) * HH + h] = s3;
}

// ---- gate partials: grid (16 bblk, 20 seg, 2 sel), block 512 ----
__global__ __launch_bounds__(512) void k_gpart(
    const float* __restrict__ x, const float* __restrict__ ctx,
    const float* __restrict__ hidden,
    const float* __restrict__ Wxr, const float* __restrict__ Whr,
    const float* __restrict__ Wxz, const float* __restrict__ Whz,
    float* __restrict__ gp) {
  int b0 = blockIdx.x * 4, seg = blockIdx.y, sel = blockIdx.z, h = threadIdx.x;
  const float* Wx = sel ? Wxz : Wxr;
  const float* Wh = sel ? Whz : Whr;
  float* outp = gp + (size_t)(sel * 20 + seg) * BB * HH;
  part_seg(Wx, Wh, x, ctx, hidden, seg, b0, h, outp);
}

// ---- gate reduce: r,z = sigmoid(bias + sum partials); emit z, rh=r*hidden ----
__global__ __launch_bounds__(512) void k_gred(
    const float* __restrict__ gp, const float* __restrict__ Wxrb,
    const float* __restrict__ Wxzb, const float* __restrict__ hidden,
    float* __restrict__ z_out, float* __restrict__ rh_out) {
  int b = blockIdx.x, h = threadIdx.x;
  float r = Wxrb[h], z = Wxzb[h];
#pragma unroll
  for (int s = 0; s < 20; ++s) {
    r += gp[((size_t)s * BB + b) * HH + h];
    z += gp[((size_t)(20 + s) * BB + b) * HH + h];
  }
  r = fast_sigmoid(r);
  z_out[b * HH + h] = fast_sigmoid(z);
  rh_out[b * HH + h] = r * hidden[b * HH + h];
}

// ---- newh partials: grid (16 bblk, 20 seg), block 512; hv = rh ----
__global__ __launch_bounds__(512) void k_npart(
    const float* __restrict__ x, const float* __restrict__ ctx,
    const float* __restrict__ rh,
    const float* __restrict__ Wxh, const float* __restrict__ Whh,
    float* __restrict__ np) {
  int b0 = blockIdx.x * 4, seg = blockIdx.y, h = threadIdx.x;
  float* outp = np + (size_t)seg * BB * HH;
  part_seg(Wxh, Whh, x, ctx, rh, seg, b0, h, outp);
}

// ---- newh reduce: h~ = tanh(bias + sum); nh = z*h + (1-z)*h~; emit f32 + bf16 ----
__global__ __launch_bounds__(512) void k_nred(
    const float* __restrict__ np, const float* __restrict__ Wxhb,
    const float* __restrict__ z, const float* __restrict__ hidden,
    float* __restrict__ nh, unsigned short* __restrict__ nhbf) {
  int b = blockIdx.x, h = threadIdx.x;
  float a = Wxhb[h];
#pragma unroll
  for (int s = 0; s < 20; ++s) a += np[((size_t)s * BB + b) * HH + h];
  float ht = fast_tanh(a);
  float zz = z[b * HH + h];
  float val = zz * hidden[b * HH + h] + (1.0f - zz) * ht;
  nh[b * HH + h] = val;
  nhbf[b * HH + h] = f2bf(val);
}

// ---- output projection via MFMA: out[64,32000] = nh_bf16 @ Who + bias ----
__global__ __launch_bounds__(256) void k_out2(const unsigned short* __restrict__ nhbf,
                                              const float* __restrict__ Who,
                                              const float* __restrict__ Whob,
                                              float* __restrict__ out) {
  int tid = threadIdx.x;
  int lane = tid & 63, w = tid >> 6;
  int l15 = lane & 15, quad = lane >> 4;
  int n = blockIdx.x * 64 + w * 16 + l15;

  floatx4 acc[4];
#pragma unroll
  for (int i = 0; i < 4; ++i) acc[i] = (floatx4)0.0f;

#pragma unroll
  for (int kc = 0; kc < 16; ++kc) {
    int k0 = kc * 32;
    float bf[8];
    const float* bp = Who + (size_t)(k0 + quad * 8) * OUTD + n;
#pragma unroll
    for (int j = 0; j < 8; ++j) bf[j] = bp[(size_t)j * OUTD];
    union { unsigned u[4]; short8 v; } bu;
#pragma unroll
    for (int j = 0; j < 4; ++j) bu.u[j] = pk2(bf[2 * j], bf[2 * j + 1]);
#pragma unroll
    for (int i = 0; i < 4; ++i) {
      short8 af = *(const short8*)(nhbf + (i * 16 + l15) * HH + k0 + quad * 8);
      acc[i] = __builtin_amdgcn_mfma_f32_16x16x32_bf16(af, bu.v, acc[i], 0, 0, 0);
    }
  }
  float bias = Whob[n];
#pragma unroll
  for (int i = 0; i < 4; ++i)
#pragma unroll
    for (int r = 0; r < 4; ++r) {
      int m = i * 16 + quad * 4 + r;
      out[(size_t)m * OUTD + n] = acc[i][r] + bias;
    }
}

extern "C" void kernel_launch(void* const* d_in, const int* in_sizes, int n_in,
                              void* d_out, int out_size, void* d_ws, size_t ws_size,
                              hipStream_t stream) {
  const float* x    = (const float*)d_in[0];
  const float* hid  = (const float*)d_in[1];
  const float* enc  = (const float*)d_in[2];
  const float* W1w  = (const float*)d_in[3];
  const float* W1b  = (const float*)d_in[4];
  const float* W2w  = (const float*)d_in[5];
  const float* vw   = (const float*)d_in[6];
  const float* Wxr  = (const float*)d_in[7];
  const float* Wxrb = (const float*)d_in[8];
  const float* Whr  = (const float*)d_in[9];
  const float* Wxz  = (const float*)d_in[10];
  const float* Wxzb = (const float*)d_in[11];
  const float* Whz  = (const float*)d_in[12];
  const float* Wxh  = (const float*)d_in[13];
  const float* Wxhb = (const float*)d_in[14];
  const float* Whh  = (const float*)d_in[15];
  const float* Who  = (const float*)d_in[16];
  const float* Whob = (const float*)d_in[17];

  float* out  = (float*)d_out;                    // [64,32000]
  float* nh   = out + (size_t)BB * OUTD;          // [64,512]
  float* attn = nh + (size_t)BB * HH;             // [64,2048]

  char* ws = (char*)d_ws;
  unsigned short* W1t  = (unsigned short*)(ws + WS_W1T);
  float* hbp  = (float*)(ws + WS_HBP);
  float* ctx  = (float*)(ws + WS_CTX);
  unsigned short* nhbf = (unsigned short*)(ws + WS_NHBF);
  float* zg   = (float*)(ws + WS_Z);
  float* rh   = (float*)(ws + WS_RH);
  float* gp   = (float*)(ws + WS_GP);
  float* np   = (float*)(ws + WS_NP);
  float* ctxp = (float*)(ws + WS_CTXP);
  float* sump = (float*)(ws + WS_SUMP);
  unsigned short* encb = (unsigned short*)(ws + WS_ENCB);

  k_prep<<<512, 256, 0, stream>>>(W1w, W1t);
  k_conv<<<(BB * SS) / 32, 256, 0, stream>>>(enc, encb);
  k_hb<<<dim3(16, 8), 256, 0, stream>>>(hid, W2w, W1b, hbp);
  k_scores<<<(BB * SS) / 64, 256, 0, stream>>>(encb, W1t, hbp, vw, attn, ctxp, sump);
  k_norm<<<BB, 512, 0, stream>>>(attn, ctxp, sump, ctx);
  k_gpart<<<dim3(16, 20, 2), 512, 0, stream>>>(x, ctx, hid, Wxr, Whr, Wxz, Whz, gp);
  k_gred<<<BB, 512, 0, stream>>>(gp, Wxrb, Wxzb, hid, zg, rh);
  k_npart<<<dim3(16, 20), 512, 0, stream>>>(x, ctx, rh, Wxh, Whh, np);
  k_nred<<<BB, 512, 0, stream>>>(np, Wxhb, zg, hid, nh, nhbf);
  k_out2<<<500, 256, 0, stream>>>(nhbf, Who, Whob, out);
}

// Round 8
// 585.148 us; speedup vs baseline: 1.0128x; 1.0128x over previous
//
#include <hip/hip_runtime.h>

// Problem dims
#define BB 64
#define SS 2048
#define INDIM 256
#define HH 512
#define EE 256
#define OUTD 32000

typedef __attribute__((ext_vector_type(8))) short short8;
typedef __attribute__((ext_vector_type(4))) float floatx4;

#define LOG2E 1.4426950408889634f

// ---- helpers ----
__device__ __forceinline__ unsigned short f2bf(float f) {
  unsigned u = __float_as_uint(f);
  return (unsigned short)((u + 0x7FFFu + ((u >> 16) & 1u)) >> 16);  // RNE
}
__device__ __forceinline__ unsigned pk2(float a, float b) {
  return (unsigned)f2bf(a) | ((unsigned)f2bf(b) << 16);
}
__device__ __forceinline__ float bf2f(unsigned short u) {
  return __uint_as_float((unsigned)u << 16);
}
__device__ __forceinline__ float fast_tanh(float x) {
  float e = __builtin_amdgcn_exp2f(x * 2.8853900817779268f);
  return 1.0f - 2.0f * __builtin_amdgcn_rcpf(e + 1.0f);
}
__device__ __forceinline__ float fast_sigmoid(float x) {
  float e = __builtin_amdgcn_exp2f(-x * LOG2E);
  return __builtin_amdgcn_rcpf(1.0f + e);
}

// global -> LDS 16B DMA (zero VGPR data path; vmcnt-tracked)
typedef __attribute__((address_space(1))) const void g1void;
typedef __attribute__((address_space(3))) void l3void;
__device__ __forceinline__ void dma16(const void* g, void* l) {
  __builtin_amdgcn_global_load_lds((g1void*)g, (l3void*)l, 16, 0, 0);
}

// ws layout (bytes)
#define WS_W1T   0          // 256x512 bf16 W1^T              : 262144
#define WS_HBP   262144     // 8 x 64x256 f32 hb partials     : 524288
#define WS_CTX   786432     // 64x512 f32 normalized ctx      : 131072
#define WS_NHBF  917504     // 64x512 bf16 new hidden         : 65536
#define WS_GP    1245184    // 40 x 64x512 f32 gate partials  : 5242880
#define WS_NP    6488064    // 20 x 64x512 f32 newh partials  : 2621440
#define WS_CTXP  9109504    // 8192x512 f32 ctx partials      : 16777216
#define WS_SUMP  25886720   // 2048 f32 exp-sum partials      : 8192
#define WS_ENCB  25894912   // 131072x512 bf16 swizzled enc   : 134217728

// ---- fused pre-pass: enc conv (blocks 0..4095) + W1 transpose (4096..4607)
//      + hb partials (4608..4735). All independent, input-only work.
__global__ __launch_bounds__(256) void k_pre(
    const float* __restrict__ enc, unsigned short* __restrict__ encb,
    const float* __restrict__ W1, unsigned short* __restrict__ W1t,
    const float* __restrict__ hidden, const float* __restrict__ W2,
    const float* __restrict__ W1b, float* __restrict__ hbp) {
  int blk = blockIdx.x, tid = threadIdx.x;
  if (blk < 4096) {
    // conv: enc f32 -> bf16, bank-swizzled row layout (chunk c -> c^(r&7))
    int r_loc = tid >> 3, c0 = tid & 7;
    int row = blk * 32 + r_loc;
    int rs = row & 7;
    const float* src = enc + (size_t)row * HH;
    unsigned short* dst = encb + (size_t)row * HH;
#pragma unroll
    for (int k = 0; k < 8; ++k) {
      int c = c0 + k * 8;
      float4 f0 = *(const float4*)(src + c * 8);
      float4 f1 = *(const float4*)(src + c * 8 + 4);
      uint4 w;
      w.x = pk2(f0.x, f0.y); w.y = pk2(f0.z, f0.w);
      w.z = pk2(f1.x, f1.y); w.w = pk2(f1.z, f1.w);
      *(uint4*)(dst + (c ^ rs) * 8) = w;
    }
  } else if (blk < 4608) {
    // prep: W1 [k][e] -> W1t bf16 [e][k]
    int idx = (blk - 4096) * 256 + tid;
    int k = idx >> 8, e = idx & 255;
    W1t[e * HH + k] = f2bf(W1[idx]);
  } else {
    // hb partials: 128 units = 16 bblk x 8 seg (K-split 64), unrolled loads
    int u = blk - 4608;
    int b0 = (u & 15) * 4, seg = u >> 4, e = tid;
    int h0 = seg * 64;
    float a0 = 0, a1 = 0, a2 = 0, a3 = 0;
    if (seg == 0) { a0 = a1 = a2 = a3 = W1b[e]; }
#pragma unroll 16
    for (int h = 0; h < 64; ++h) {
      float w = W2[(h0 + h) * EE + e];
      a0 += hidden[(b0 + 0) * HH + h0 + h] * w;
      a1 += hidden[(b0 + 1) * HH + h0 + h] * w;
      a2 += hidden[(b0 + 2) * HH + h0 + h] * w;
      a3 += hidden[(b0 + 3) * HH + h0 + h] * w;
    }
    float* o = hbp + (size_t)seg * BB * EE;
    o[(b0 + 0) * EE + e] = a0; o[(b0 + 1) * EE + e] = a1;
    o[(b0 + 2) * EE + e] = a2; o[(b0 + 3) * EE + e] = a3;
  }
}

// ---- fused scores + exp + unnormalized context partials (bf16 input) ----
// (R6 structure: linear DMA of pre-swizzled bf16 rows, one barrier,
//  barrier-free unrolled MFMA phase, swizzled conflict-free LDS reads.)
__global__ __launch_bounds__(256, 2) void k_scores(
    const unsigned short* __restrict__ encb, const unsigned short* __restrict__ W1t,
    const float* __restrict__ hbp, const float* __restrict__ vw,
    float* __restrict__ attn, float* __restrict__ ctxp, float* __restrict__ sump) {
  __shared__ unsigned short Afull[64 * 512];   // 65536 B, swizzled chunks
  __shared__ float hb_s[EE], v_s[EE];
  __shared__ float red[4 * 64];
  __shared__ float wbuf[64];

  int tid = threadIdx.x;
  int m0 = blockIdx.x * 64;
  int b = blockIdx.x >> 5;                 // 32 tiles per batch
  int sloc = (blockIdx.x & 31) * 64;
  int lane = tid & 63, wn = tid >> 6;      // wave = one 64-wide N tile
  int l15 = lane & 15, quad = lane >> 4;

#pragma unroll
  for (int rr = 0; rr < 16; ++rr) {
    int r = wn * 16 + rr;
    dma16(encb + (size_t)(m0 + r) * HH + lane * 8, Afull + r * HH);
  }
  {
    float hbv = 0.0f;
#pragma unroll
    for (int s = 0; s < 8; ++s) hbv += hbp[s * BB * EE + b * EE + tid];
    hb_s[tid] = hbv;
    v_s[tid] = vw[tid];
  }
  __syncthreads();   // drains DMA + LDS writes; tile valid

  floatx4 acc[4][4];
#pragma unroll
  for (int i = 0; i < 4; ++i)
#pragma unroll
    for (int j = 0; j < 4; ++j) acc[i][j] = (floatx4)0.0f;

  const unsigned short* bbase = W1t + (size_t)(wn * 64) * HH;
#pragma unroll
  for (int kb = 0; kb < 16; ++kb) {
    short8 a[4];
#pragma unroll
    for (int i = 0; i < 4; ++i) {
      int r = i * 16 + l15;
      int pc = (kb * 4 + quad) ^ (l15 & 7);      // phys 16B chunk
      a[i] = *(const short8*)(Afull + r * HH + pc * 8);
    }
#pragma unroll
    for (int j = 0; j < 4; ++j) {
      short8 bfr = *(const short8*)(bbase + (size_t)(j * 16 + l15) * HH + kb * 32 + quad * 8);
#pragma unroll
      for (int i = 0; i < 4; ++i)
        acc[i][j] = __builtin_amdgcn_mfma_f32_16x16x32_bf16(a[i], bfr, acc[i][j], 0, 0, 0);
    }
  }
  __syncthreads();

#pragma unroll
  for (int i = 0; i < 4; ++i)
#pragma unroll
    for (int r = 0; r < 4; ++r) {
      float s = 0.0f;
#pragma unroll
      for (int j = 0; j < 4; ++j) {
        int e = wn * 64 + j * 16 + l15;
        s += fast_tanh(acc[i][j][r] + hb_s[e]) * v_s[e];
      }
#pragma unroll
      for (int off = 1; off < 16; off <<= 1) s += __shfl_xor(s, off, 64);
      if (l15 == 0) red[wn * 64 + i * 16 + quad * 4 + r] = s;
    }
  __syncthreads();
  if (tid < 64) {
    float sc = red[tid] + red[64 + tid] + red[128 + tid] + red[192 + tid];
    float e = __builtin_amdgcn_exp2f(sc * LOG2E);   // |sc| <= sum|v| ~ 13: safe
    wbuf[tid] = e;
    attn[b * SS + sloc + tid] = e;                  // unnormalized; k_norm divides
    float s = e;
#pragma unroll
    for (int off = 1; off < 64; off <<= 1) s += __shfl_xor(s, off, 64);
    if (tid == 0) sump[blockIdx.x] = s;
  }
  __syncthreads();

  float cacc[8];
#pragma unroll
  for (int j = 0; j < 8; ++j) cacc[j] = 0.0f;
#pragma unroll
  for (int rr = 0; rr < 16; ++rr) {
    int r = wn * 16 + rr;
    float w = wbuf[r];
    int pc = lane ^ (r & 7);
    short8 av = *(const short8*)(Afull + r * HH + pc * 8);
#pragma unroll
    for (int j = 0; j < 8; ++j) cacc[j] += w * bf2f((unsigned short)av[j]);
  }
  float4 c0, c1;
  c0.x = cacc[0]; c0.y = cacc[1]; c0.z = cacc[2]; c0.w = cacc[3];
  c1.x = cacc[4]; c1.y = cacc[5]; c1.z = cacc[6]; c1.w = cacc[7];
  float* cp = ctxp + ((size_t)blockIdx.x * 4 + wn) * HH + lane * 8;
  *(float4*)cp = c0;
  *(float4*)(cp + 4) = c1;
}

// ---- reduce partials, normalize attn + ctx; grid 128 (64 b x 2 half) ----
__global__ __launch_bounds__(256) void k_norm(float* __restrict__ attn,
                                              const float* __restrict__ ctxp,
                                              const float* __restrict__ sump,
                                              float* __restrict__ ctx) {
  int b = blockIdx.x >> 1, half = blockIdx.x & 1, tid = threadIdx.x;
  float s = 0.0f;
#pragma unroll
  for (int t = 0; t < 32; ++t) s += sump[b * 32 + t];
  float inv = 1.0f / s;
  int h = half * 256 + tid;
  float c = 0.0f;
#pragma unroll 16
  for (int t = 0; t < 128; ++t) c += ctxp[(size_t)(b * 128 + t) * HH + h];
  ctx[b * HH + h] = c * inv;
#pragma unroll
  for (int i = 0; i < 4; ++i) attn[b * SS + half * 1024 + i * 256 + tid] *= inv;
}

// ---- K-split partial GEMM core: 64 virtual-K rows, 4 batches ----
// virtual K layout [ x(256) | ctx(512) | hv(512) ]; loads unrolled 16-deep.
__device__ __forceinline__ void part_seg(
    const float* __restrict__ Wx, const float* __restrict__ Wh,
    const float* __restrict__ x, const float* __restrict__ ctx,
    const float* __restrict__ hv, int seg, int b0, int h,
    float* __restrict__ outp) {
  const float* wseg;
  const float* a0; const float* a1; const float* a2; const float* a3;
  int vk0 = seg * 64;
  if (seg < 4) {
    wseg = Wx + (size_t)vk0 * HH;
    a0 = x + (b0 + 0) * INDIM + vk0;       a1 = x + (b0 + 1) * INDIM + vk0;
    a2 = x + (b0 + 2) * INDIM + vk0;       a3 = x + (b0 + 3) * INDIM + vk0;
  } else if (seg < 12) {
    wseg = Wx + (size_t)vk0 * HH;
    int off = vk0 - 256;
    a0 = ctx + (b0 + 0) * HH + off;        a1 = ctx + (b0 + 1) * HH + off;
    a2 = ctx + (b0 + 2) * HH + off;        a3 = ctx + (b0 + 3) * HH + off;
  } else {
    int off = vk0 - 768;
    wseg = Wh + (size_t)off * HH;
    a0 = hv + (b0 + 0) * HH + off;         a1 = hv + (b0 + 1) * HH + off;
    a2 = hv + (b0 + 2) * HH + off;         a3 = hv + (b0 + 3) * HH + off;
  }
  float s0 = 0, s1 = 0, s2 = 0, s3 = 0;
#pragma unroll 16
  for (int i = 0; i < 64; ++i) {
    float w = wseg[i * HH + h];
    s0 += a0[i] * w; s1 += a1[i] * w;
    s2 += a2[i] * w; s3 += a3[i] * w;
  }
  outp[(b0 + 0) * HH + h] = s0; outp[(b0 + 1) * HH + h] = s1;
  outp[(b0 + 2) * HH + h] = s2; outp[(b0 + 3) * HH + h] = s3;
}

// ---- gate partials: grid (16 bblk, 20 seg, 2 sel), block 512 ----
__global__ __launch_bounds__(512) void k_gpart(
    const float* __restrict__ x, const float* __restrict__ ctx,
    const float* __restrict__ hidden,
    const float* __restrict__ Wxr, const float* __restrict__ Whr,
    const float* __restrict__ Wxz, const float* __restrict__ Whz,
    float* __restrict__ gp) {
  int b0 = blockIdx.x * 4, seg = blockIdx.y, sel = blockIdx.z, h = threadIdx.x;
  const float* Wx = sel ? Wxz : Wxr;
  const float* Wh = sel ? Whz : Whr;
  float* outp = gp + (size_t)(sel * 20 + seg) * BB * HH;
  part_seg(Wx, Wh, x, ctx, hidden, seg, b0, h, outp);
}

// ---- newh partials: grid (16 bblk, 20 seg), block 512 ----
// r-gate inlined: for hv segs (>=12), the needed 4x64 rh slice is computed
// in-block from gp (same op order as the old k_gred: bias + s-ascending sum,
// sigmoid, times hidden -> bit-identical), eliminating the k_gred launch.
__global__ __launch_bounds__(512) void k_npart(
    const float* __restrict__ x, const float* __restrict__ ctx,
    const float* __restrict__ hidden, const float* __restrict__ gp,
    const float* __restrict__ Wxrb,
    const float* __restrict__ Wxh, const float* __restrict__ Whh,
    float* __restrict__ np) {
  __shared__ float rh_s[256];
  int b0 = blockIdx.x * 4, seg = blockIdx.y, h = threadIdx.x;
  int vk0 = seg * 64;
  const float* wseg;
  const float* a0; const float* a1; const float* a2; const float* a3;
  if (seg >= 12) {
    int off = vk0 - 768;
    if (h < 256) {
      int bb = h >> 6, k = off + (h & 63);
      float r = Wxrb[k];
#pragma unroll
      for (int s = 0; s < 20; ++s) r += gp[((size_t)s * BB + b0 + bb) * HH + k];
      rh_s[h] = fast_sigmoid(r) * hidden[(b0 + bb) * HH + k];
    }
    __syncthreads();
    wseg = Whh + (size_t)off * HH;
    a0 = rh_s; a1 = rh_s + 64; a2 = rh_s + 128; a3 = rh_s + 192;
  } else if (seg < 4) {
    wseg = Wxh + (size_t)vk0 * HH;
    a0 = x + (b0 + 0) * INDIM + vk0;       a1 = x + (b0 + 1) * INDIM + vk0;
    a2 = x + (b0 + 2) * INDIM + vk0;       a3 = x + (b0 + 3) * INDIM + vk0;
  } else {
    int off = vk0 - 256;
    wseg = Wxh + (size_t)vk0 * HH;
    a0 = ctx + (b0 + 0) * HH + off;        a1 = ctx + (b0 + 1) * HH + off;
    a2 = ctx + (b0 + 2) * HH + off;        a3 = ctx + (b0 + 3) * HH + off;
  }
  float s0 = 0, s1 = 0, s2 = 0, s3 = 0;
#pragma unroll 16
  for (int i = 0; i < 64; ++i) {
    float w = wseg[i * HH + h];
    s0 += a0[i] * w; s1 += a1[i] * w;
    s2 += a2[i] * w; s3 += a3[i] * w;
  }
  float* outp = np + (size_t)seg * BB * HH;
  outp[(b0 + 0) * HH + h] = s0; outp[(b0 + 1) * HH + h] = s1;
  outp[(b0 + 2) * HH + h] = s2; outp[(b0 + 3) * HH + h] = s3;
}

// ---- newh reduce (z-gate inlined): grid 128 (64 b x 2 half), block 256 ----
__global__ __launch_bounds__(256) void k_nred(
    const float* __restrict__ np, const float* __restrict__ gp,
    const float* __restrict__ Wxzb, const float* __restrict__ Wxhb,
    const float* __restrict__ hidden,
    float* __restrict__ nh, unsigned short* __restrict__ nhbf) {
  int b = blockIdx.x >> 1, h = (blockIdx.x & 1) * 256 + threadIdx.x;
  float z = Wxzb[h];
#pragma unroll
  for (int s = 0; s < 20; ++s) z += gp[((size_t)(20 + s) * BB + b) * HH + h];
  z = fast_sigmoid(z);
  float a = Wxhb[h];
#pragma unroll
  for (int s = 0; s < 20; ++s) a += np[((size_t)s * BB + b) * HH + h];
  float ht = fast_tanh(a);
  float val = z * hidden[b * HH + h] + (1.0f - z) * ht;
  nh[b * HH + h] = val;
  nhbf[b * HH + h] = f2bf(val);
}

// ---- output projection via MFMA: out[64,32000] = nh_bf16 @ Who + bias ----
__global__ __launch_bounds__(256) void k_out2(const unsigned short* __restrict__ nhbf,
                                              const float* __restrict__ Who,
                                              const float* __restrict__ Whob,
                                              float* __restrict__ out) {
  int tid = threadIdx.x;
  int lane = tid & 63, w = tid >> 6;
  int l15 = lane & 15, quad = lane >> 4;
  int n = blockIdx.x * 64 + w * 16 + l15;

  floatx4 acc[4];
#pragma unroll
  for (int i = 0; i < 4; ++i) acc[i] = (floatx4)0.0f;

#pragma unroll
  for (int kc = 0; kc < 16; ++kc) {
    int k0 = kc * 32;
    float bf[8];
    const float* bp = Who + (size_t)(k0 + quad * 8) * OUTD + n;
#pragma unroll
    for (int j = 0; j < 8; ++j) bf[j] = bp[(size_t)j * OUTD];
    union { unsigned u[4]; short8 v; } bu;
#pragma unroll
    for (int j = 0; j < 4; ++j) bu.u[j] = pk2(bf[2 * j], bf[2 * j + 1]);
#pragma unroll
    for (int i = 0; i < 4; ++i) {
      short8 af = *(const short8*)(nhbf + (i * 16 + l15) * HH + k0 + quad * 8);
      acc[i] = __builtin_amdgcn_mfma_f32_16x16x32_bf16(af, bu.v, acc[i], 0, 0, 0);
    }
  }
  float bias = Whob[n];
#pragma unroll
  for (int i = 0; i < 4; ++i)
#pragma unroll
    for (int r = 0; r < 4; ++r) {
      int m = i * 16 + quad * 4 + r;
      out[(size_t)m * OUTD + n] = acc[i][r] + bias;
    }
}

extern "C" void kernel_launch(void* const* d_in, const int* in_sizes, int n_in,
                              void* d_out, int out_size, void* d_ws, size_t ws_size,
                              hipStream_t stream) {
  const float* x    = (const float*)d_in[0];
  const float* hid  = (const float*)d_in[1];
  const float* enc  = (const float*)d_in[2];
  const float* W1w  = (const float*)d_in[3];
  const float* W1b  = (const float*)d_in[4];
  const float* W2w  = (const float*)d_in[5];
  const float* vw   = (const float*)d_in[6];
  const float* Wxr  = (const float*)d_in[7];
  const float* Wxrb = (const float*)d_in[8];
  const float* Whr  = (const float*)d_in[9];
  const float* Wxz  = (const float*)d_in[10];
  const float* Wxzb = (const float*)d_in[11];
  const float* Whz  = (const float*)d_in[12];
  const float* Wxh  = (const float*)d_in[13];
  const float* Wxhb = (const float*)d_in[14];
  const float* Whh  = (const float*)d_in[15];
  const float* Who  = (const float*)d_in[16];
  const float* Whob = (const float*)d_in[17];

  float* out  = (float*)d_out;                    // [64,32000]
  float* nh   = out + (size_t)BB * OUTD;          // [64,512]
  float* attn = nh + (size_t)BB * HH;             // [64,2048]

  char* ws = (char*)d_ws;
  unsigned short* W1t  = (unsigned short*)(ws + WS_W1T);
  float* hbp  = (float*)(ws + WS_HBP);
  float* ctx  = (float*)(ws + WS_CTX);
  unsigned short* nhbf = (unsigned short*)(ws + WS_NHBF);
  float* gp   = (float*)(ws + WS_GP);
  float* np   = (float*)(ws + WS_NP);
  float* ctxp = (float*)(ws + WS_CTXP);
  float* sump = (float*)(ws + WS_SUMP);
  unsigned short* encb = (unsigned short*)(ws + WS_ENCB);

  k_pre<<<4736, 256, 0, stream>>>(enc, encb, W1w, W1t, hid, W2w, W1b, hbp);
  k_scores<<<(BB * SS) / 64, 256, 0, stream>>>(encb, W1t, hbp, vw, attn, ctxp, sump);
  k_norm<<<128, 256, 0, stream>>>(attn, ctxp, sump, ctx);
  k_gpart<<<dim3(16, 20, 2), 512, 0, stream>>>(x, ctx, hid, Wxr, Whr, Wxz, Whz, gp);
  k_npart<<<dim3(16, 20), 512, 0, stream>>>(x, ctx, hid, gp, Wxrb, Wxh, Whh, np);
  k_nred<<<128, 256, 0, stream>>>(np, gp, Wxzb, Wxhb, hid, nh, nhbf);
  k_out2<<<500, 256, 0, stream>>>(nhbf, Who, Whob, out);
}

// Round 9
// 508.803 us; speedup vs baseline: 1.1648x; 1.1501x over previous
//
#include <hip/hip_runtime.h>

// Problem dims
#define BB 64
#define SS 2048
#define INDIM 256
#define HH 512
#define EE 256
#define OUTD 32000

typedef __attribute__((ext_vector_type(8))) short short8;
typedef __attribute__((ext_vector_type(4))) float floatx4;

#define LOG2E 1.4426950408889634f

// ---- helpers ----
__device__ __forceinline__ unsigned short f2bf(float f) {
  unsigned u = __float_as_uint(f);
  return (unsigned short)((u + 0x7FFFu + ((u >> 16) & 1u)) >> 16);  // RNE
}
__device__ __forceinline__ unsigned pk2(float a, float b) {
  return (unsigned)f2bf(a) | ((unsigned)f2bf(b) << 16);
}
__device__ __forceinline__ float bf2f(unsigned short u) {
  return __uint_as_float((unsigned)u << 16);
}
__device__ __forceinline__ float fast_tanh(float x) {
  float e = __builtin_amdgcn_exp2f(x * 2.8853900817779268f);
  return 1.0f - 2.0f * __builtin_amdgcn_rcpf(e + 1.0f);
}
__device__ __forceinline__ float fast_sigmoid(float x) {
  float e = __builtin_amdgcn_exp2f(-x * LOG2E);
  return __builtin_amdgcn_rcpf(1.0f + e);
}

// ws layout (bytes)
#define WS_W1T   0          // 256x512 bf16 W1^T              : 262144
#define WS_HBP   262144     // 8 x 64x256 f32 hb partials     : 524288
#define WS_CTX   786432     // 64x512 f32 normalized ctx      : 131072
#define WS_NHBF  917504     // 64x512 bf16 new hidden         : 65536
#define WS_GP    1245184    // 40 x 64x512 f32 gate partials  : 5242880
#define WS_NP    6488064    // 20 x 64x512 f32 newh partials  : 2621440
#define WS_CTXP  9109504    // 8192x512 f32 ctx partials      : 16777216
#define WS_SUMP  25886720   // 2048 f32 exp-sum partials      : 8192

// ---- fused pre-pass: W1 transpose (blocks 0..511) + hb partials (512..639) ----
__global__ __launch_bounds__(256) void k_pre(
    const float* __restrict__ W1, unsigned short* __restrict__ W1t,
    const float* __restrict__ hidden, const float* __restrict__ W2,
    const float* __restrict__ W1b, float* __restrict__ hbp) {
  int blk = blockIdx.x, tid = threadIdx.x;
  if (blk < 512) {
    // prep: W1 [k][e] -> W1t bf16 [e][k]
    int idx = blk * 256 + tid;
    int k = idx >> 8, e = idx & 255;
    W1t[e * HH + k] = f2bf(W1[idx]);
  } else {
    // hb partials: 128 units = 16 bblk x 8 seg (K-split 64), unrolled loads
    int u = blk - 512;
    int b0 = (u & 15) * 4, seg = u >> 4, e = tid;
    int h0 = seg * 64;
    float a0 = 0, a1 = 0, a2 = 0, a3 = 0;
    if (seg == 0) { a0 = a1 = a2 = a3 = W1b[e]; }
#pragma unroll 16
    for (int h = 0; h < 64; ++h) {
      float w = W2[(h0 + h) * EE + e];
      a0 += hidden[(b0 + 0) * HH + h0 + h] * w;
      a1 += hidden[(b0 + 1) * HH + h0 + h] * w;
      a2 += hidden[(b0 + 2) * HH + h0 + h] * w;
      a3 += hidden[(b0 + 3) * HH + h0 + h] * w;
    }
    float* o = hbp + (size_t)seg * BB * EE;
    o[(b0 + 0) * EE + e] = a0; o[(b0 + 1) * EE + e] = a1;
    o[(b0 + 2) * EE + e] = a2; o[(b0 + 3) * EE + e] = a3;
  }
}

// ---- fused scores + exp + unnormalized context partials ----
// R1 structure (best measured, ~140us): grid 2048 (BS/64), block 256 (4 waves
// = 4 N-tiles), 64x512 enc tile in LDS bf16. Depth-3 register prefetch; raw
// lgkm-only barrier per chunk (vmcnt never drained -> enc prefetch loads stay
// in flight across barriers); W1t B-frags prefetched one chunk ahead.
#define LDA 520   // 512 k + 8 pad shorts: 1040B row (16B-mult)
__global__ __launch_bounds__(256) void k_scores(
    const float* __restrict__ enc, const unsigned short* __restrict__ W1t,
    const float* __restrict__ hbp, const float* __restrict__ vw,
    float* __restrict__ attn, float* __restrict__ ctxp, float* __restrict__ sump) {
  __shared__ unsigned short Afull[64 * LDA];   // 66560 B
  __shared__ float hb_s[EE], v_s[EE];
  __shared__ float red[4 * 64];
  __shared__ float wbuf[64];

  int tid = threadIdx.x;
  int m0 = blockIdx.x * 64;
  int b = blockIdx.x >> 5;                 // 32 tiles per batch
  int sloc = (blockIdx.x & 31) * 64;
  {
    float hbv = 0.0f;
#pragma unroll
    for (int s = 0; s < 8; ++s) hbv += hbp[s * BB * EE + b * EE + tid];
    hb_s[tid] = hbv;
    v_s[tid] = vw[tid];
  }

  int lane = tid & 63, wn = tid >> 6;      // wave = one 64-wide N tile
  int l15 = lane & 15, quad = lane >> 4;

  // staging assignment: thread covers (row0,kg) and (row0+32,kg), fixed all chunks
  int row0 = tid >> 3, kg = tid & 7;
  const float* base0 = enc + (size_t)(m0 + row0) * HH + kg * 4;
  const float* base1 = enc + (size_t)(m0 + 32 + row0) * HH + kg * 4;

  floatx4 acc[4][4];
#pragma unroll
  for (int i = 0; i < 4; ++i)
#pragma unroll
    for (int j = 0; j < 4; ++j) acc[i][j] = (floatx4)0.0f;

  float4 pf0[3], pf1[3];
#pragma unroll
  for (int d = 0; d < 3; ++d) {
    pf0[d] = *(const float4*)(base0 + d * 32);
    pf1[d] = *(const float4*)(base1 + d * 32);
  }

  // B-fragments for chunk 0
  short8 bcur[4];
#pragma unroll
  for (int j = 0; j < 4; ++j)
    bcur[j] = *(const short8*)(W1t + (wn * 64 + j * 16 + l15) * HH + quad * 8);

#pragma unroll
  for (int kb = 0; kb < 16; ++kb) {
    int slot = kb % 3;
    {  // ds_write chunk kb (loads issued 3 chunks ago; counted vmcnt at use)
      float4 f = pf0[slot];
      uint2 w; w.x = pk2(f.x, f.y); w.y = pk2(f.z, f.w);
      *(uint2*)(Afull + row0 * LDA + kb * 32 + kg * 4) = w;
      f = pf1[slot];
      uint2 w2; w2.x = pk2(f.x, f.y); w2.y = pk2(f.z, f.w);
      *(uint2*)(Afull + (row0 + 32) * LDA + kb * 32 + kg * 4) = w2;
    }
    if (kb + 3 < 16) {  // issue enc prefetch for chunk kb+3
      pf0[slot] = *(const float4*)(base0 + (kb + 3) * 32);
      pf1[slot] = *(const float4*)(base1 + (kb + 3) * 32);
    }
    short8 bnx[4];
    if (kb + 1 < 16) {  // W1t B-frag prefetch for chunk kb+1 (L2-resident)
      int kkn = (kb + 1) * 32 + quad * 8;
#pragma unroll
      for (int j = 0; j < 4; ++j)
        bnx[j] = *(const short8*)(W1t + (wn * 64 + j * 16 + l15) * HH + kkn);
    }
    // write-visibility only: lgkmcnt(0) drains ds_write; vmcnt left alone.
    asm volatile("s_waitcnt lgkmcnt(0)" ::: "memory");
    __builtin_amdgcn_s_barrier();
    int kk = kb * 32 + quad * 8;
    short8 a[4];
#pragma unroll
    for (int i = 0; i < 4; ++i)
      a[i] = *(const short8*)(Afull + (i * 16 + l15) * LDA + kk);
#pragma unroll
    for (int j = 0; j < 4; ++j)
#pragma unroll
      for (int i = 0; i < 4; ++i)
        acc[i][j] = __builtin_amdgcn_mfma_f32_16x16x32_bf16(a[i], bcur[j], acc[i][j], 0, 0, 0);
    if (kb + 1 < 16) {
#pragma unroll
      for (int j = 0; j < 4; ++j) bcur[j] = bnx[j];
    }
  }
  __syncthreads();

  // score epilogue: score[m] = sum_e tanh(C+hb[e])*v[e]; C/D: col(e)=l15, row=quad*4+r
#pragma unroll
  for (int i = 0; i < 4; ++i)
#pragma unroll
    for (int r = 0; r < 4; ++r) {
      float s = 0.0f;
#pragma unroll
      for (int j = 0; j < 4; ++j) {
        int e = wn * 64 + j * 16 + l15;
        s += fast_tanh(acc[i][j][r] + hb_s[e]) * v_s[e];
      }
#pragma unroll
      for (int off = 1; off < 16; off <<= 1) s += __shfl_xor(s, off, 64);
      if (l15 == 0) red[wn * 64 + i * 16 + quad * 4 + r] = s;
    }
  __syncthreads();
  if (tid < 64) {
    float sc = red[tid] + red[64 + tid] + red[128 + tid] + red[192 + tid];
    float e = __builtin_amdgcn_exp2f(sc * LOG2E);   // |sc| <= sum|v| ~ 13: safe
    wbuf[tid] = e;
    attn[b * SS + sloc + tid] = e;                  // unnormalized; k_norm divides
    float s = e;
#pragma unroll
    for (int off = 1; off < 64; off <<= 1) s += __shfl_xor(s, off, 64);
    if (tid == 0) sump[blockIdx.x] = s;
  }
  __syncthreads();

  // pass 2: ctx partials from the LDS tile. Wave wn covers rows [wn*16,+16);
  // all 64 lanes read one full 1KB row slice per step.
  float cacc[8];
#pragma unroll
  for (int j = 0; j < 8; ++j) cacc[j] = 0.0f;
#pragma unroll
  for (int rr = 0; rr < 16; ++rr) {
    int r = wn * 16 + rr;
    float w = wbuf[r];
    short8 av = *(const short8*)(Afull + r * LDA + lane * 8);
#pragma unroll
    for (int j = 0; j < 8; ++j) cacc[j] += w * bf2f((unsigned short)av[j]);
  }
  float4 c0, c1;
  c0.x = cacc[0]; c0.y = cacc[1]; c0.z = cacc[2]; c0.w = cacc[3];
  c1.x = cacc[4]; c1.y = cacc[5]; c1.z = cacc[6]; c1.w = cacc[7];
  float* cp = ctxp + ((size_t)blockIdx.x * 4 + wn) * HH + lane * 8;
  *(float4*)cp = c0;
  *(float4*)(cp + 4) = c1;
}

// ---- reduce partials, normalize attn + ctx; grid 128 (64 b x 2 half) ----
__global__ __launch_bounds__(256) void k_norm(float* __restrict__ attn,
                                              const float* __restrict__ ctxp,
                                              const float* __restrict__ sump,
                                              float* __restrict__ ctx) {
  int b = blockIdx.x >> 1, half = blockIdx.x & 1, tid = threadIdx.x;
  float s = 0.0f;
#pragma unroll
  for (int t = 0; t < 32; ++t) s += sump[b * 32 + t];
  float inv = 1.0f / s;
  int h = half * 256 + tid;
  float c = 0.0f;
#pragma unroll 16
  for (int t = 0; t < 128; ++t) c += ctxp[(size_t)(b * 128 + t) * HH + h];
  ctx[b * HH + h] = c * inv;
#pragma unroll
  for (int i = 0; i < 4; ++i) attn[b * SS + half * 1024 + i * 256 + tid] *= inv;
}

// ---- K-split partial GEMM core: 64 virtual-K rows, 4 batches ----
// virtual K layout [ x(256) | ctx(512) | hv(512) ]; loads unrolled 16-deep.
__device__ __forceinline__ void part_seg(
    const float* __restrict__ Wx, const float* __restrict__ Wh,
    const float* __restrict__ x, const float* __restrict__ ctx,
    const float* __restrict__ hv, int seg, int b0, int h,
    float* __restrict__ outp) {
  const float* wseg;
  const float* a0; const float* a1; const float* a2; const float* a3;
  int vk0 = seg * 64;
  if (seg < 4) {
    wseg = Wx + (size_t)vk0 * HH;
    a0 = x + (b0 + 0) * INDIM + vk0;       a1 = x + (b0 + 1) * INDIM + vk0;
    a2 = x + (b0 + 2) * INDIM + vk0;       a3 = x + (b0 + 3) * INDIM + vk0;
  } else if (seg < 12) {
    wseg = Wx + (size_t)vk0 * HH;
    int off = vk0 - 256;
    a0 = ctx + (b0 + 0) * HH + off;        a1 = ctx + (b0 + 1) * HH + off;
    a2 = ctx + (b0 + 2) * HH + off;        a3 = ctx + (b0 + 3) * HH + off;
  } else {
    int off = vk0 - 768;
    wseg = Wh + (size_t)off * HH;
    a0 = hv + (b0 + 0) * HH + off;         a1 = hv + (b0 + 1) * HH + off;
    a2 = hv + (b0 + 2) * HH + off;         a3 = hv + (b0 + 3) * HH + off;
  }
  float s0 = 0, s1 = 0, s2 = 0, s3 = 0;
#pragma unroll 16
  for (int i = 0; i < 64; ++i) {
    float w = wseg[i * HH + h];
    s0 += a0[i] * w; s1 += a1[i] * w;
    s2 += a2[i] * w; s3 += a3[i] * w;
  }
  outp[(b0 + 0) * HH + h] = s0; outp[(b0 + 1) * HH + h] = s1;
  outp[(b0 + 2) * HH + h] = s2; outp[(b0 + 3) * HH + h] = s3;
}

// ---- gate partials: grid (16 bblk, 20 seg, 2 sel), block 512 ----
__global__ __launch_bounds__(512) void k_gpart(
    const float* __restrict__ x, const float* __restrict__ ctx,
    const float* __restrict__ hidden,
    const float* __restrict__ Wxr, const float* __restrict__ Whr,
    const float* __restrict__ Wxz, const float* __restrict__ Whz,
    float* __restrict__ gp) {
  int b0 = blockIdx.x * 4, seg = blockIdx.y, sel = blockIdx.z, h = threadIdx.x;
  const float* Wx = sel ? Wxz : Wxr;
  const float* Wh = sel ? Whz : Whr;
  float* outp = gp + (size_t)(sel * 20 + seg) * BB * HH;
  part_seg(Wx, Wh, x, ctx, hidden, seg, b0, h, outp);
}

// ---- newh partials: grid (16 bblk, 20 seg), block 512 ----
// r-gate inlined for hv segs (>=12): the 4x64 rh slice is computed in-block
// from gp (bias + s-ascending sum, sigmoid, times hidden -> bit-identical to
// a separate gred pass), eliminating that launch.
__global__ __launch_bounds__(512) void k_npart(
    const float* __restrict__ x, const float* __restrict__ ctx,
    const float* __restrict__ hidden, const float* __restrict__ gp,
    const float* __restrict__ Wxrb,
    const float* __restrict__ Wxh, const float* __restrict__ Whh,
    float* __restrict__ np) {
  __shared__ float rh_s[256];
  int b0 = blockIdx.x * 4, seg = blockIdx.y, h = threadIdx.x;
  int vk0 = seg * 64;
  const float* wseg;
  const float* a0; const float* a1; const float* a2; const float* a3;
  if (seg >= 12) {
    int off = vk0 - 768;
    if (h < 256) {
      int bb = h >> 6, k = off + (h & 63);
      float r = Wxrb[k];
#pragma unroll
      for (int s = 0; s < 20; ++s) r += gp[((size_t)s * BB + b0 + bb) * HH + k];
      rh_s[h] = fast_sigmoid(r) * hidden[(b0 + bb) * HH + k];
    }
    __syncthreads();
    wseg = Whh + (size_t)off * HH;
    a0 = rh_s; a1 = rh_s + 64; a2 = rh_s + 128; a3 = rh_s + 192;
  } else if (seg < 4) {
    wseg = Wxh + (size_t)vk0 * HH;
    a0 = x + (b0 + 0) * INDIM + vk0;       a1 = x + (b0 + 1) * INDIM + vk0;
    a2 = x + (b0 + 2) * INDIM + vk0;       a3 = x + (b0 + 3) * INDIM + vk0;
  } else {
    int off = vk0 - 256;
    wseg = Wxh + (size_t)vk0 * HH;
    a0 = ctx + (b0 + 0) * HH + off;        a1 = ctx + (b0 + 1) * HH + off;
    a2 = ctx + (b0 + 2) * HH + off;        a3 = ctx + (b0 + 3) * HH + off;
  }
  float s0 = 0, s1 = 0, s2 = 0, s3 = 0;
#pragma unroll 16
  for (int i = 0; i < 64; ++i) {
    float w = wseg[i * HH + h];
    s0 += a0[i] * w; s1 += a1[i] * w;
    s2 += a2[i] * w; s3 += a3[i] * w;
  }
  float* outp = np + (size_t)seg * BB * HH;
  outp[(b0 + 0) * HH + h] = s0; outp[(b0 + 1) * HH + h] = s1;
  outp[(b0 + 2) * HH + h] = s2; outp[(b0 + 3) * HH + h] = s3;
}

// ---- newh reduce (z-gate inlined): grid 128 (64 b x 2 half), block 256 ----
__global__ __launch_bounds__(256) void k_nred(
    const float* __restrict__ np, const float* __restrict__ gp,
    const float* __restrict__ Wxzb, const float* __restrict__ Wxhb,
    const float* __restrict__ hidden,
    float* __restrict__ nh, unsigned short* __restrict__ nhbf) {
  int b = blockIdx.x >> 1, h = (blockIdx.x & 1) * 256 + threadIdx.x;
  float z = Wxzb[h];
#pragma unroll
  for (int s = 0; s < 20; ++s) z += gp[((size_t)(20 + s) * BB + b) * HH + h];
  z = fast_sigmoid(z);
  float a = Wxhb[h];
#pragma unroll
  for (int s = 0; s < 20; ++s) a += np[((size_t)s * BB + b) * HH + h];
  float ht = fast_tanh(a);
  float val = z * hidden[b * HH + h] + (1.0f - z) * ht;
  nh[b * HH + h] = val;
  nhbf[b * HH + h] = f2bf(val);
}

// ---- output projection via MFMA: out[64,32000] = nh_bf16 @ Who + bias ----
__global__ __launch_bounds__(256) void k_out2(const unsigned short* __restrict__ nhbf,
                                              const float* __restrict__ Who,
                                              const float* __restrict__ Whob,
                                              float* __restrict__ out) {
  int tid = threadIdx.x;
  int lane = tid & 63, w = tid >> 6;
  int l15 = lane & 15, quad = lane >> 4;
  int n = blockIdx.x * 64 + w * 16 + l15;

  floatx4 acc[4];
#pragma unroll
  for (int i = 0; i < 4; ++i) acc[i] = (floatx4)0.0f;

#pragma unroll
  for (int kc = 0; kc < 16; ++kc) {
    int k0 = kc * 32;
    float bf[8];
    const float* bp = Who + (size_t)(k0 + quad * 8) * OUTD + n;
#pragma unroll
    for (int j = 0; j < 8; ++j) bf[j] = bp[(size_t)j * OUTD];
    union { unsigned u[4]; short8 v; } bu;
#pragma unroll
    for (int j = 0; j < 4; ++j) bu.u[j] = pk2(bf[2 * j], bf[2 * j + 1]);
#pragma unroll
    for (int i = 0; i < 4; ++i) {
      short8 af = *(const short8*)(nhbf + (i * 16 + l15) * HH + k0 + quad * 8);
      acc[i] = __builtin_amdgcn_mfma_f32_16x16x32_bf16(af, bu.v, acc[i], 0, 0, 0);
    }
  }
  float bias = Whob[n];
#pragma unroll
  for (int i = 0; i < 4; ++i)
#pragma unroll
    for (int r = 0; r < 4; ++r) {
      int m = i * 16 + quad * 4 + r;
      out[(size_t)m * OUTD + n] = acc[i][r] + bias;
    }
}

extern "C" void kernel_launch(void* const* d_in, const int* in_sizes, int n_in,
                              void* d_out, int out_size, void* d_ws, size_t ws_size,
                              hipStream_t stream) {
  const float* x    = (const float*)d_in[0];
  const float* hid  = (const float*)d_in[1];
  const float* enc  = (const float*)d_in[2];
  const float* W1w  = (const float*)d_in[3];
  const float* W1b  = (const float*)d_in[4];
  const float* W2w  = (const float*)d_in[5];
  const float* vw   = (const float*)d_in[6];
  const float* Wxr  = (const float*)d_in[7];
  const float* Wxrb = (const float*)d_in[8];
  const float* Whr  = (const float*)d_in[9];
  const float* Wxz  = (const float*)d_in[10];
  const float* Wxzb = (const float*)d_in[11];
  const float* Whz  = (const float*)d_in[12];
  const float* Wxh  = (const float*)d_in[13];
  const float* Wxhb = (const float*)d_in[14];
  const float* Whh  = (const float*)d_in[15];
  const float* Who  = (const float*)d_in[16];
  const float* Whob = (const float*)d_in[17];

  float* out  = (float*)d_out;                    // [64,32000]
  float* nh   = out + (size_t)BB * OUTD;          // [64,512]
  float* attn = nh + (size_t)BB * HH;             // [64,2048]

  char* ws = (char*)d_ws;
  unsigned short* W1t  = (unsigned short*)(ws + WS_W1T);
  float* hbp  = (float*)(ws + WS_HBP);
  float* ctx  = (float*)(ws + WS_CTX);
  unsigned short* nhbf = (unsigned short*)(ws + WS_NHBF);
  float* gp   = (float*)(ws + WS_GP);
  float* np   = (float*)(ws + WS_NP);
  float* ctxp = (float*)(ws + WS_CTXP);
  float* sump = (float*)(ws + WS_SUMP);

  k_pre<<<640, 256, 0, stream>>>(W1w, W1t, hid, W2w, W1b, hbp);
  k_scores<<<(BB * SS) / 64, 256, 0, stream>>>(enc, W1t, hbp, vw, attn, ctxp, sump);
  k_norm<<<128, 256, 0, stream>>>(attn, ctxp, sump, ctx);
  k_gpart<<<dim3(16, 20, 2), 512, 0, stream>>>(x, ctx, hid, Wxr, Whr, Wxz, Whz, gp);
  k_npart<<<dim3(16, 20), 512, 0, stream>>>(x, ctx, hid, gp, Wxrb, Wxh, Whh, np);
  k_nred<<<128, 256, 0, stream>>>(np, gp, Wxzb, Wxhb, hid, nh, nhbf);
  k_out2<<<500, 256, 0, stream>>>(nhbf, Who, Whob, out);
}